// Round 8
// baseline (2697.750 us; speedup 1.0000x reference)
//
#include <hip/hip_runtime.h>
#include <hip/hip_cooperative_groups.h>

using u16 = unsigned short;
using u32 = unsigned int;
using u64 = unsigned long long;
using bf16x8 = __attribute__((ext_vector_type(8))) short;
using f16x8  = __attribute__((ext_vector_type(8))) _Float16;
using f32x4  = __attribute__((ext_vector_type(4))) float;
using u32x4  = __attribute__((ext_vector_type(4))) unsigned int;

// ---------------- workspace layout (bytes) ----------------
static constexpr size_t XU_OFF = 0;
static constexpr size_t XU_BYTES = (size_t)512 * 64 * 4096 * 2;      // 256 MiB
static constexpr size_t XB_OFF = XU_OFF + XU_BYTES;
static constexpr size_t XB_BYTES = (size_t)64 * 512 * 1024 * 2;      // 64 MiB
static constexpr size_t UT_OFF = XB_OFF + XB_BYTES;
static constexpr size_t WT_BYTES = (size_t)4096 * 1024 * 2;          // 8 MiB
static constexpr size_t VT_OFF = UT_OFF + WT_BYTES;
static constexpr size_t BP_OFF = VT_OFF + WT_BYTES;
static constexpr size_t BP_BYTES = 4096 * 4;
// h plane: [2 parity][4 group][16 row][1024 col] u16 (fp16)
static constexpr size_t HT_PLANE = (size_t)2 * 4 * 16 * 1024 * 2;    // 256 KiB
static constexpr size_t HHI_OFF = BP_OFF + BP_BYTES;
static constexpr size_t FLAG_OFF = HHI_OFF + HT_PLANE;
// flags[g*64+cb] (u32[0..255]); 4096 B region

__device__ __forceinline__ float bf2f(u32 u) {
    return __uint_as_float(u << 16);
}
__device__ __forceinline__ u16 f2bf(float f) {
    u32 u = __float_as_uint(f);
    u32 r = (u + 0x7FFFu + ((u >> 16) & 1u)) >> 16;
    return (u16)r;
}
__device__ __forceinline__ u16 f2h(float f) {
    _Float16 x = (_Float16)f;                     // RTN
    union { _Float16 h; u16 u; } cv;
    cv.h = x;
    return cv.u;
}

// fast gates: v_exp + v_rcp (err ~1e-7, far below bf16 pipeline noise)
__device__ __forceinline__ float fast_sigmoid(float x) {
    return __builtin_amdgcn_rcpf(1.f + __expf(-x));
}
__device__ __forceinline__ float fast_tanh(float x) {
    return 1.f - 2.f * __builtin_amdgcn_rcpf(1.f + __expf(2.f * x));
}

// 16B cache-bypassing load (full-64B-line MALL requests)
__device__ __forceinline__ u32x4 load16_uc(const u16* p) {
    u32x4 v;
    asm volatile("global_load_dwordx4 %0, %1, off sc0 sc1"
                 : "=v"(v)
                 : "v"(p));
    return v;
}

// counted wait for h load j (4 loads issued; xu prefetch may be outstanding
// and is OLDER, so vmcnt(3-j) drains it first -- oldest-first is safe).
__device__ __forceinline__ void wait_vm4(int j, u32x4& a) {
    switch (j) {
    case 0:  asm volatile("s_waitcnt vmcnt(3)" : "+v"(a)); break;
    case 1:  asm volatile("s_waitcnt vmcnt(2)" : "+v"(a)); break;
    case 2:  asm volatile("s_waitcnt vmcnt(1)" : "+v"(a)); break;
    default: asm volatile("s_waitcnt vmcnt(0)" : "+v"(a)); break;
    }
}

// async global->LDS, 16B per lane (wave-uniform LDS base + lane*16)
__device__ __forceinline__ void gld16(const u16* g, u16* l) {
    __builtin_amdgcn_global_load_lds((const __attribute__((address_space(1))) void*)g,
                                     (__attribute__((address_space(3))) void*)l,
                                     16, 0, 0);
}

// ------------- one 128x128 xU GEMM tile, 8 waves (512 threads) -------------
// Serial phase (round-8): tau = bx*32 + p with mt=tau>>5, nt=tau&31 -- each
// block computes the full nt-row for ONE mt: its 256KB A-panel becomes
// L2-resident after tile 0 and is reused 32x; UT (8MB) is L2-hot per XCD.
// Plain cached stores for xu: visibility to the scan phase is provided by the
// __threadfence + grid.sync boundary (the proven prologue handoff mechanism).
// Round-6/7 lesson: overlapped produce/consume needed write-through (sc0 sc1)
// which thrashed MALL (+290us scan interference); nt stores were worse still
// (bypass MALL -> consumer reads all-HBM). Serial + fence avoids all of it.
__device__ __forceinline__ void gemm_tile(int tau,
        const u16* __restrict__ xb, const u16* __restrict__ UT,
        const float* __restrict__ bp, u16* __restrict__ xu,
        u16* As, u16* Bs, u16* Cs) {
    int mt = tau >> 5, nt = tau & 31;
    int tid = threadIdx.x;
    int lane = tid & 63, wv = tid >> 6;
    int wm = wv >> 2, wn = wv & 3;                // 2 x 4 wave grid
    int l15 = lane & 15, quad = lane >> 4;

    // staging: 512 threads x 16B = 8KB = one full [128][32] tile per inst
    int idr = tid >> 2, idk = (tid & 3) * 8;
    const u16* aS = xb + (size_t)(mt * 128 + idr) * 1024 + idk;
    const u16* bS = UT + (size_t)(nt * 128 + idr) * 1024 + idk;
    u16* aD = As + (size_t)tid * 8;
    u16* bD = Bs + (size_t)tid * 8;

    f32x4 acc[4][2];
#pragma unroll
    for (int i = 0; i < 4; ++i)
#pragma unroll
        for (int j = 0; j < 2; ++j) acc[i][j] = f32x4{0.f, 0.f, 0.f, 0.f};

    float biasv[2];
#pragma unroll
    for (int j = 0; j < 2; ++j) biasv[j] = bp[nt * 128 + wn * 32 + j * 16 + l15];

    for (int k0 = 0; k0 < 1024; k0 += 32) {
        gld16(aS + k0, aD);
        gld16(bS + k0, bD);
        __syncthreads();                          // compiler drains vmcnt first
        bf16x8 af[4], bfv[2];
#pragma unroll
        for (int i = 0; i < 4; ++i)
            af[i] = *(const bf16x8*)(As + (size_t)(wm * 64 + i * 16 + l15) * 32 + quad * 8);
#pragma unroll
        for (int j = 0; j < 2; ++j)
            bfv[j] = *(const bf16x8*)(Bs + (size_t)(wn * 32 + j * 16 + l15) * 32 + quad * 8);
#pragma unroll
        for (int i = 0; i < 4; ++i)
#pragma unroll
            for (int j = 0; j < 2; ++j)
                acc[i][j] = __builtin_amdgcn_mfma_f32_16x16x32_bf16(af[i], bfv[j], acc[i][j], 0, 0, 0);
        __syncthreads();                          // protect LDS before next stage
    }

    // acc -> LDS C-tile (row-pad 136 u16 kills the 64-aligned bank repeat)
#pragma unroll
    for (int i = 0; i < 4; ++i)
#pragma unroll
        for (int j = 0; j < 2; ++j)
#pragma unroll
            for (int rg = 0; rg < 4; ++rg)
                Cs[(size_t)(wm * 64 + i * 16 + quad * 4 + rg) * 136 + wn * 32 + j * 16 + l15] =
                    f2bf(acc[i][j][rg] + biasv[j]);
    __syncthreads();

    // coalesced plain cached stores: 16 lanes cover one 256B row-segment.
    // No per-tile drain -- the phase-end __threadfence covers visibility.
#pragma unroll
    for (int p = 0; p < 4; ++p) {
        int id = p * 512 + tid;
        int row = id >> 4, q = id & 15;
        u32x4 v = *(const u32x4*)(Cs + (size_t)row * 136 + q * 8);
        int gr = mt * 128 + row;
        int t_i = gr & 511, b_i = gr >> 9;
        *(u32x4*)(xu + (((size_t)(t_i * 64 + b_i)) << 12) + nt * 128 + q * 8) = v;
    }
    __syncthreads();                              // Cs reuse protection
}

// ------------- single fused kernel: prep + full-GPU xU GEMM + recurrent scan -------------
// 256 blocks x 512 threads, 1/CU (118KB LDS). PROLOGUE (all blocks): zero
// flags (block 0), bias pack (block 1), x fp32->bf16, U/V repack -- then
// grid.sync. GEMM PHASE: all 256 blocks, 32 tiles each (mt=bx), ~280us,
// zero interference design (round-6 showed overlap inflates the scan +75%
// for a net ~0 win). Then __threadfence + grid.sync (cross-XCD visibility,
// mechanism proven by the prologue handoff in rounds 6/7). SCAN: blocks
// 0..127 run the round-5-verbatim scan in full isolation; 128..255 exit.
__global__ void __launch_bounds__(512, 2) lstm_fused_kernel(
        const float* __restrict__ x,
        const float* U0, const float* V0, const float* b0,
        const float* U1, const float* V1, const float* b1,
        const float* U2, const float* V2, const float* b2,
        const float* U3, const float* V3, const float* b3,
        char* __restrict__ ws, float* __restrict__ out) {
    __shared__ u16 As[128 * 32];                  // 8 KB
    __shared__ u16 Bs[128 * 32];                  // 8 KB
    __shared__ u16 Cs[128 * 136];                 // 34 KB (also repack tile)
    __shared__ float zs[8][16][132];              // 67.6 KB

    u16*   xb  = (u16*)(ws + XB_OFF);
    u16*   UT  = (u16*)(ws + UT_OFF);
    u16*   VT  = (u16*)(ws + VT_OFF);
    float* bp  = (float*)(ws + BP_OFF);
    u16*   xu  = (u16*)(ws + XU_OFF);
    u16*   hhi = (u16*)(ws + HHI_OFF);
    u32*   flags = (u32*)(ws + FLAG_OFF);

    int bx = blockIdx.x;
    int tid = threadIdx.x;

    // ---- PROLOGUE ----
    if (bx == 0) {   // zero flags straight to MALL
        __hip_atomic_store(flags + tid, 0u, __ATOMIC_RELAXED, __HIP_MEMORY_SCOPE_AGENT);
        __hip_atomic_store(flags + 512 + tid, 0u, __ATOMIC_RELAXED, __HIP_MEMORY_SCOPE_AGENT);
    }
    if (bx == 1) {   // bias pack: bp[hc*4+g] = b_g[hc]
        const float* bsrc[4] = {b0, b1, b2, b3};
#pragma unroll
        for (int it = 0; it < 8; ++it) {
            int n = it * 512 + tid;
            bp[n] = bsrc[n & 3][n >> 2];
        }
    }
    {   // x fp32 -> bf16 (all blocks; 64 x 131072 float4 = full 33.5M elems)
        const float4* x4 = (const float4*)x;
        uint2* xb4 = (uint2*)xb;
        int t0 = bx * 512 + tid;
#pragma unroll 4
        for (int k = 0; k < 64; ++k) {
            int idx = t0 + k * 131072;
            float4 v = x4[idx];
            uint2 o;
            o.x = (u32)f2bf(v.x) | ((u32)f2bf(v.y) << 16);
            o.y = (u32)f2bf(v.z) | ((u32)f2bf(v.w) << 16);
            xb4[idx] = o;
        }
    }
    {   // U/V repack (verbatim round-5 body; 8 virtual 64x64 tiles per block)
        u16* tile = Cs;                           // [64][65] u16 inside Cs
        const float* srcs[8] = {U0, U1, U2, U3, V0, V1, V2, V3};
        for (int vb = 0; vb < 8; ++vb) {
            int vbx = bx * 8 + vb;
            int mat = vbx >> 8, rem = vbx & 255;
            int tf = rem >> 4, th = rem & 15;
            int f0 = tf * 64, h0 = th * 64;
            const float* s = srcs[mat];
            u16* d = (mat < 4) ? UT : VT;
            bool isU = (mat < 4);
            int gg = mat & 3;
            if (tid < 256) {
                int cc = tid & 63, rr = tid >> 6;
#pragma unroll
                for (int i = 0; i < 16; ++i) {
                    int fr = rr + i * 4;
                    float v = s[(size_t)(f0 + fr) * 1024 + h0 + cc];
                    tile[fr * 65 + cc] = isU ? f2bf(v) : f2h(v);
                }
            }
            __syncthreads();
            if (tid < 256) {
                int cc = tid & 63, rr = tid >> 6;
#pragma unroll
                for (int i = 0; i < 16; ++i) {
                    int hcl = rr + i * 4;
                    d[(size_t)((h0 + hcl) * 4 + gg) * 1024 + f0 + cc] = tile[cc * 65 + hcl];
                }
            }
            __syncthreads();
        }
    }
    __threadfence();                              // publish xb/UT/VT/bp
    cooperative_groups::this_grid().sync();

    // ---- GEMM PHASE: all 8192 tiles on all 256 blocks (mt = bx) ----
    for (int p = 0; p < 32; ++p)
        gemm_tile(bx * 32 + p, xb, UT, bp, xu, As, Bs, Cs);
    __threadfence();                              // publish xu cross-XCD
    cooperative_groups::this_grid().sync();

    if (bx >= 128) return;

    // ---- recurrent scan (round-5 proven structure, full isolation) ----
    int g  = bx & 3;
    int cb = bx >> 2;                             // 0..31
    int lane = tid & 63, wv = tid >> 6;           // wv 0..7
    int l15 = lane & 15, quad = lane >> 4;
    int r  = tid >> 5;                            // batch row within group, 0..15
    int hc = tid & 31;                            // h-col within block, 0..31

    // V fragments in registers (fp16, 128 VGPRs/lane, fixed across steps)
    f16x8 vfrag[8][4];
    {
        const u16* vb = VT + ((size_t)(cb * 128 + l15) * 1024) + wv * 128 + quad * 8;
#pragma unroll
        for (int nt = 0; nt < 8; ++nt)
#pragma unroll
            for (int j = 0; j < 4; ++j)
                vfrag[nt][j] = *(const f16x8*)(vb + (size_t)nt * 16 * 1024 + j * 32);
    }

    u32* gflags = flags + g * 64;
    int myp = 4 * wv + (lane & 3);                // producer polled by this lane

    float c = 0.f;
    float h = 0.f;

    uint2 xraw = *(const uint2*)(xu + ((size_t)(g * 16 + r) << 12) + cb * 128 + hc * 4);

    for (int t = 0; t < 512; ++t) {
        f32x4 acc[8];
#pragma unroll
        for (int nt = 0; nt < 8; ++nt) acc[nt] = f32x4{0.f, 0.f, 0.f, 0.f};

        if (t) {
            // 1) poll this wave's 4 producers (lanes replicate x16; ballot all-set)
            for (;;) {
                u32 f = __hip_atomic_load(gflags + myp, __ATOMIC_RELAXED,
                                          __HIP_MEMORY_SCOPE_AGENT);
                if (__ballot(f >= (u32)t) == ~0ull) break;
                __builtin_amdgcn_s_sleep(1);
            }
            asm volatile("" ::: "memory");        // keep h loads below the poll

            // 2) stream h fragments: 4x16B uncached loads, full-line MALL reads
            const u16* hB = hhi + (((size_t)(t & 1) * 4 + g) * 16 + l15) * 1024
                          + wv * 128 + quad * 8;
            u32x4 hv[4];
#pragma unroll
            for (int j = 0; j < 4; ++j)
                hv[j] = load16_uc(hB + j * 32);
#pragma unroll
            for (int j = 0; j < 4; ++j) {
                wait_vm4(j, hv[j]);               // counted wait, ties block MFMA hoist
                union { u32x4 q; f16x8 v; } ah;
                ah.q = hv[j];
#pragma unroll
                for (int nt = 0; nt < 8; ++nt)
                    acc[nt] = __builtin_amdgcn_mfma_f32_16x16x32_f16(ah.v, vfrag[nt][j], acc[nt], 0, 0, 0);
            }
        }

        // 3) split-K partial handoff: C layout col=l15, row=quad*4+rg
#pragma unroll
        for (int nt = 0; nt < 8; ++nt)
#pragma unroll
            for (int rg = 0; rg < 4; ++rg)
                zs[wv][quad * 4 + rg][nt * 16 + l15] = acc[nt][rg];
        __syncthreads();

        float4 s = {0.f, 0.f, 0.f, 0.f};
#pragma unroll
        for (int w = 0; w < 8; ++w) {
            float4 v = *(const float4*)&zs[w][r][hc * 4];
            s.x += v.x; s.y += v.y; s.z += v.z; s.w += v.w;
        }
        float z0 = s.x + bf2f(xraw.x & 0xFFFFu);
        float z1 = s.y + bf2f(xraw.x >> 16);
        float z2 = s.z + bf2f(xraw.y & 0xFFFFu);
        float z3 = s.w + bf2f(xraw.y >> 16);

        float it_ = fast_sigmoid(z0);
        float ft_ = fast_sigmoid(z1);
        float gt_ = fast_tanh(z2);
        float ot_ = fast_tanh(z3);   // reference uses tanh for output gate
        c = ft_ * c + it_ * gt_;
        h = ot_ * fast_tanh(c);

        if (t == 511) break;     // final h never read back

        // 4) publish h (single fp16 write-through) + drain (stores only) + flag
        size_t sidx = (((size_t)((t + 1) & 1) * 4 + g) * 16 + r) * 1024 + cb * 32 + hc;
        __hip_atomic_store(hhi + sidx, f2h(h), __ATOMIC_RELAXED,
                           __HIP_MEMORY_SCOPE_AGENT);
        asm volatile("s_waitcnt vmcnt(0)" ::: "memory");
        __syncthreads();          // also protects zs reuse next iteration
        if (tid == 0)
            __hip_atomic_store(gflags + cb, (u32)(t + 1), __ATOMIC_RELAXED,
                               __HIP_MEMORY_SCOPE_AGENT);

        // 5) prefetch next xu AFTER the flag: its latency hides under
        //    the next poll window instead of sitting in the publish drain.
        xraw = *(const uint2*)(xu + ((size_t)((t + 1) * 64 + g * 16 + r) << 12) + cb * 128 + hc * 4);
    }

    out[(size_t)(g * 16 + r) * 1024 + cb * 32 + hc] = h;
}

extern "C" void kernel_launch(void* const* d_in, const int* in_sizes, int n_in,
                              void* d_out, int out_size, void* d_ws, size_t ws_size,
                              hipStream_t stream) {
    char* ws = (char*)d_ws;
    const float* x = (const float*)d_in[0];
    const float *U[4], *V[4], *b[4];
    for (int g = 0; g < 4; ++g) {
        U[g] = (const float*)d_in[1 + 3 * g];
        V[g] = (const float*)d_in[2 + 3 * g];
        b[g] = (const float*)d_in[3 + 3 * g];
    }
    float* out = (float*)d_out;

    void* args[] = {(void*)&x,
                    (void*)&U[0], (void*)&V[0], (void*)&b[0],
                    (void*)&U[1], (void*)&V[1], (void*)&b[1],
                    (void*)&U[2], (void*)&V[2], (void*)&b[2],
                    (void*)&U[3], (void*)&V[3], (void*)&b[3],
                    (void*)&ws, (void*)&out};
    hipLaunchCooperativeKernel((const void*)lstm_fused_kernel, dim3(256), dim3(512),
                               args, 0, stream);
}

// Round 9
// 2342.804 us; speedup vs baseline: 1.1515x; 1.1515x over previous
//
#include <hip/hip_runtime.h>
#include <hip/hip_cooperative_groups.h>

using u16 = unsigned short;
using u32 = unsigned int;
using u64 = unsigned long long;
using bf16x8 = __attribute__((ext_vector_type(8))) short;
using f16x8  = __attribute__((ext_vector_type(8))) _Float16;
using f32x4  = __attribute__((ext_vector_type(4))) float;
using u32x4  = __attribute__((ext_vector_type(4))) unsigned int;

// ---------------- workspace layout (bytes) ----------------
static constexpr size_t XU_OFF = 0;
static constexpr size_t XU_BYTES = (size_t)512 * 64 * 4096 * 2;      // 256 MiB
static constexpr size_t XB_OFF = XU_OFF + XU_BYTES;
static constexpr size_t XB_BYTES = (size_t)64 * 512 * 1024 * 2;      // 64 MiB
static constexpr size_t UT_OFF = XB_OFF + XB_BYTES;
static constexpr size_t WT_BYTES = (size_t)4096 * 1024 * 2;          // 8 MiB
static constexpr size_t VT_OFF = UT_OFF + WT_BYTES;
static constexpr size_t BP_OFF = VT_OFF + WT_BYTES;
static constexpr size_t BP_BYTES = 4096 * 4;
// h plane: [2 parity][4 group][16 row][1024 col] u16 (fp16)
static constexpr size_t HT_PLANE = (size_t)2 * 4 * 16 * 1024 * 2;    // 256 KiB
static constexpr size_t HHI_OFF = BP_OFF + BP_BYTES;
static constexpr size_t FLAG_OFF = HHI_OFF + HT_PLANE;
// flags[g*64+cb] (u32[0..255]) + chunk cnt (u32[512..515]); 4096 B total

__device__ __forceinline__ float bf2f(u32 u) {
    return __uint_as_float(u << 16);
}
__device__ __forceinline__ u16 f2bf(float f) {
    u32 u = __float_as_uint(f);
    u32 r = (u + 0x7FFFu + ((u >> 16) & 1u)) >> 16;
    return (u16)r;
}
__device__ __forceinline__ u16 f2h(float f) {
    _Float16 x = (_Float16)f;                     // RTN
    union { _Float16 h; u16 u; } cv;
    cv.h = x;
    return cv.u;
}

// fast gates: v_exp + v_rcp (err ~1e-7, far below bf16 pipeline noise)
__device__ __forceinline__ float fast_sigmoid(float x) {
    return __builtin_amdgcn_rcpf(1.f + __expf(-x));
}
__device__ __forceinline__ float fast_tanh(float x) {
    return 1.f - 2.f * __builtin_amdgcn_rcpf(1.f + __expf(2.f * x));
}

// 16B cache-bypassing load (full-64B-line MALL requests)
__device__ __forceinline__ u32x4 load16_uc(const u16* p) {
    u32x4 v;
    asm volatile("global_load_dwordx4 %0, %1, off sc0 sc1"
                 : "=v"(v)
                 : "v"(p));
    return v;
}

// 16B write-through store, MALL-ALLOCATING. sc0 sc1 = MALL-visible (required
// for cross-XCD produce/consume of xu inside ONE kernel). NO nt flag:
// round-7/8 lesson -- nt bypasses MALL allocation, turning the scan's xu
// prefetches into HBM misses (FETCH 686->768MB, kernel +450us); plain cached
// stores (round 8) thrash MALL with dirty writebacks (FETCH 1.38GB). The
// allocating write-through keeps xu MALL-resident for the consumer.
__device__ __forceinline__ void store16_wt(u16* p, u32x4 v) {
    asm volatile("global_store_dwordx4 %0, %1, off sc0 sc1"
                 :: "v"(p), "v"(v) : "memory");
}

// counted wait for h load j (4 loads issued; xu prefetch may be outstanding
// and is OLDER, so vmcnt(3-j) drains it first -- oldest-first is safe).
__device__ __forceinline__ void wait_vm4(int j, u32x4& a) {
    switch (j) {
    case 0:  asm volatile("s_waitcnt vmcnt(3)" : "+v"(a)); break;
    case 1:  asm volatile("s_waitcnt vmcnt(2)" : "+v"(a)); break;
    case 2:  asm volatile("s_waitcnt vmcnt(1)" : "+v"(a)); break;
    default: asm volatile("s_waitcnt vmcnt(0)" : "+v"(a)); break;
    }
}

// async global->LDS, 16B per lane (wave-uniform LDS base + lane*16)
__device__ __forceinline__ void gld16(const u16* g, u16* l) {
    __builtin_amdgcn_global_load_lds((const __attribute__((address_space(1))) void*)g,
                                     (__attribute__((address_space(3))) void*)l,
                                     16, 0, 0);
}

// xu t-chunk readiness gate (2048 tiles per chunk)
__device__ __forceinline__ void wait_chunk(const u32* cnt, int c) {
    for (;;) {
        u32 v = __hip_atomic_load(cnt + c, __ATOMIC_RELAXED, __HIP_MEMORY_SCOPE_AGENT);
        if (v >= 2048u) break;
        __builtin_amdgcn_s_sleep(8);
    }
    asm volatile("" ::: "memory");   // keep xu loads below the gate
}

// ------------- one 128x128 xU GEMM tile, 8 waves (512 threads) -------------
// Chunk-ordered tile index tau: tc=tau>>11 (t-chunk), b=(tau&2047)>>5, nt=tau&31,
// mt=b*4+tc. LDS-staged (one gld16 per matrix per K-step), MFMA 4x2 per wave.
// Epilogue: acc -> LDS C-tile (bf16+bias) -> coalesced 256B-per-16-lane
// write-through stores -> vmcnt drain -> barrier -> chunk counter bump.
__device__ __forceinline__ void gemm_tile(int tau,
        const u16* __restrict__ xb, const u16* __restrict__ UT,
        const float* __restrict__ bp, u16* __restrict__ xu,
        u16* As, u16* Bs, u16* Cs, u32* cnt) {
    int tc = tau >> 11, rem = tau & 2047;
    int b = rem >> 5, nt = rem & 31, mt = b * 4 + tc;
    int tid = threadIdx.x;
    int lane = tid & 63, wv = tid >> 6;
    int wm = wv >> 2, wn = wv & 3;                // 2 x 4 wave grid
    int l15 = lane & 15, quad = lane >> 4;

    // staging: 512 threads x 16B = 8KB = one full [128][32] tile per inst
    int idr = tid >> 2, idk = (tid & 3) * 8;
    const u16* aS = xb + (size_t)(mt * 128 + idr) * 1024 + idk;
    const u16* bS = UT + (size_t)(nt * 128 + idr) * 1024 + idk;
    u16* aD = As + (size_t)tid * 8;
    u16* bD = Bs + (size_t)tid * 8;

    f32x4 acc[4][2];
#pragma unroll
    for (int i = 0; i < 4; ++i)
#pragma unroll
        for (int j = 0; j < 2; ++j) acc[i][j] = f32x4{0.f, 0.f, 0.f, 0.f};

    float biasv[2];
#pragma unroll
    for (int j = 0; j < 2; ++j) biasv[j] = bp[nt * 128 + wn * 32 + j * 16 + l15];

    for (int k0 = 0; k0 < 1024; k0 += 32) {
        gld16(aS + k0, aD);
        gld16(bS + k0, bD);
        __syncthreads();                          // compiler drains vmcnt first
        bf16x8 af[4], bfv[2];
#pragma unroll
        for (int i = 0; i < 4; ++i)
            af[i] = *(const bf16x8*)(As + (size_t)(wm * 64 + i * 16 + l15) * 32 + quad * 8);
#pragma unroll
        for (int j = 0; j < 2; ++j)
            bfv[j] = *(const bf16x8*)(Bs + (size_t)(wn * 32 + j * 16 + l15) * 32 + quad * 8);
#pragma unroll
        for (int i = 0; i < 4; ++i)
#pragma unroll
            for (int j = 0; j < 2; ++j)
                acc[i][j] = __builtin_amdgcn_mfma_f32_16x16x32_bf16(af[i], bfv[j], acc[i][j], 0, 0, 0);
        __syncthreads();                          // protect LDS before next stage
    }

    // acc -> LDS C-tile (row-pad 136 u16 kills the 64-aligned bank repeat)
#pragma unroll
    for (int i = 0; i < 4; ++i)
#pragma unroll
        for (int j = 0; j < 2; ++j)
#pragma unroll
            for (int rg = 0; rg < 4; ++rg)
                Cs[(size_t)(wm * 64 + i * 16 + quad * 4 + rg) * 136 + wn * 32 + j * 16 + l15] =
                    f2bf(acc[i][j][rg] + biasv[j]);
    __syncthreads();

    // coalesced write-through: 16 lanes cover one 256B row-segment
#pragma unroll
    for (int p = 0; p < 4; ++p) {
        int id = p * 512 + tid;
        int row = id >> 4, q = id & 15;
        u32x4 v = *(const u32x4*)(Cs + (size_t)row * 136 + q * 8);
        int gr = mt * 128 + row;
        int t_i = gr & 511, b_i = gr >> 9;
        store16_wt(xu + (((size_t)(t_i * 64 + b_i)) << 12) + nt * 128 + q * 8, v);
    }
    asm volatile("s_waitcnt vmcnt(0)" ::: "memory");
    __syncthreads();                              // all waves' stores MALL-acked
    if (tid == 0)
        __hip_atomic_fetch_add(cnt + tc, 1u, __ATOMIC_RELAXED, __HIP_MEMORY_SCOPE_AGENT);
}

// ------------- single fused kernel: prep + xU GEMM + recurrent scan -------------
// 256 blocks x 512 threads, 1/CU (118KB LDS). PROLOGUE (all blocks): zero
// flags/cnt (block 0, direct-to-MALL atomic stores), bias pack (block 1),
// x fp32->bf16, U/V repack -- then ONE grid.sync (removes 4 launches + memset,
// ~100us of gaps; handoff mechanism proven in rounds 7/8). PHASE A: all 256
// blocks build xu t-chunk 0. Then blocks 0..127 run the round-5 scan; blocks
// 128..255 build chunks 1..3 (stride-128 order; each keeps nt fixed -> its
// B-panel L2-resident) -- chunk c done far ahead of the scan's need (~c*410us).
__global__ void __launch_bounds__(512, 2) lstm_fused_kernel(
        const float* __restrict__ x,
        const float* U0, const float* V0, const float* b0,
        const float* U1, const float* V1, const float* b1,
        const float* U2, const float* V2, const float* b2,
        const float* U3, const float* V3, const float* b3,
        char* __restrict__ ws, float* __restrict__ out) {
    __shared__ u16 As[128 * 32];                  // 8 KB
    __shared__ u16 Bs[128 * 32];                  // 8 KB
    __shared__ u16 Cs[128 * 136];                 // 34 KB (also repack tile)
    __shared__ float zs[8][16][132];              // 67.6 KB

    u16*   xb  = (u16*)(ws + XB_OFF);
    u16*   UT  = (u16*)(ws + UT_OFF);
    u16*   VT  = (u16*)(ws + VT_OFF);
    float* bp  = (float*)(ws + BP_OFF);
    u16*   xu  = (u16*)(ws + XU_OFF);
    u16*   hhi = (u16*)(ws + HHI_OFF);
    u32*   flags = (u32*)(ws + FLAG_OFF);
    u32*   cnt   = (u32*)(ws + FLAG_OFF + 2048);

    int bx = blockIdx.x;
    int tid = threadIdx.x;

    // ---- PROLOGUE ----
    if (bx == 0) {   // zero flags + chunk counters straight to MALL
        __hip_atomic_store(flags + tid, 0u, __ATOMIC_RELAXED, __HIP_MEMORY_SCOPE_AGENT);
        __hip_atomic_store(flags + 512 + tid, 0u, __ATOMIC_RELAXED, __HIP_MEMORY_SCOPE_AGENT);
    }
    if (bx == 1) {   // bias pack: bp[hc*4+g] = b_g[hc]
        const float* bsrc[4] = {b0, b1, b2, b3};
#pragma unroll
        for (int it = 0; it < 8; ++it) {
            int n = it * 512 + tid;
            bp[n] = bsrc[n & 3][n >> 2];
        }
    }
    {   // x fp32 -> bf16 (all blocks; 64 x 131072 float4 = full 33.5M elems)
        const float4* x4 = (const float4*)x;
        uint2* xb4 = (uint2*)xb;
        int t0 = bx * 512 + tid;
#pragma unroll 4
        for (int k = 0; k < 64; ++k) {
            int idx = t0 + k * 131072;
            float4 v = x4[idx];
            uint2 o;
            o.x = (u32)f2bf(v.x) | ((u32)f2bf(v.y) << 16);
            o.y = (u32)f2bf(v.z) | ((u32)f2bf(v.w) << 16);
            xb4[idx] = o;
        }
    }
    {   // U/V repack (verbatim round-5 body; 8 virtual 64x64 tiles per block)
        u16* tile = Cs;                           // [64][65] u16 inside Cs
        const float* srcs[8] = {U0, U1, U2, U3, V0, V1, V2, V3};
        for (int vb = 0; vb < 8; ++vb) {
            int vbx = bx * 8 + vb;
            int mat = vbx >> 8, rem = vbx & 255;
            int tf = rem >> 4, th = rem & 15;
            int f0 = tf * 64, h0 = th * 64;
            const float* s = srcs[mat];
            u16* d = (mat < 4) ? UT : VT;
            bool isU = (mat < 4);
            int gg = mat & 3;
            if (tid < 256) {
                int cc = tid & 63, rr = tid >> 6;
#pragma unroll
                for (int i = 0; i < 16; ++i) {
                    int fr = rr + i * 4;
                    float v = s[(size_t)(f0 + fr) * 1024 + h0 + cc];
                    tile[fr * 65 + cc] = isU ? f2bf(v) : f2h(v);
                }
            }
            __syncthreads();
            if (tid < 256) {
                int cc = tid & 63, rr = tid >> 6;
#pragma unroll
                for (int i = 0; i < 16; ++i) {
                    int hcl = rr + i * 4;
                    d[(size_t)((h0 + hcl) * 4 + gg) * 1024 + f0 + cc] = tile[cc * 65 + hcl];
                }
            }
            __syncthreads();
        }
    }
    __threadfence();                              // publish xb/UT/VT/bp to MALL
    cooperative_groups::this_grid().sync();

    // ---- PHASE A: chunk 0 on the full GPU ----
    for (int p = 0; p < 8; ++p)
        gemm_tile(bx * 8 + p, xb, UT, bp, xu, As, Bs, Cs, cnt);

    if (bx >= 128) {
        // ---- PHASE B: chunks 1..3 on blocks 128..255 ----
        int gid = bx - 128;
        for (int p = 0; p < 48; ++p)
            gemm_tile(2048 + p * 128 + gid, xb, UT, bp, xu, As, Bs, Cs, cnt);
        return;
    }

    // ---- recurrent scan (round-5 proven structure) ----
    int g  = bx & 3;
    int cb = bx >> 2;                             // 0..31
    int lane = tid & 63, wv = tid >> 6;           // wv 0..7
    int l15 = lane & 15, quad = lane >> 4;
    int r  = tid >> 5;                            // batch row within group, 0..15
    int hc = tid & 31;                            // h-col within block, 0..31

    // V fragments in registers (fp16, 128 VGPRs/lane, fixed across steps)
    f16x8 vfrag[8][4];
    {
        const u16* vb = VT + ((size_t)(cb * 128 + l15) * 1024) + wv * 128 + quad * 8;
#pragma unroll
        for (int nt = 0; nt < 8; ++nt)
#pragma unroll
            for (int j = 0; j < 4; ++j)
                vfrag[nt][j] = *(const f16x8*)(vb + (size_t)nt * 16 * 1024 + j * 32);
    }

    u32* gflags = flags + g * 64;
    int myp = 4 * wv + (lane & 3);                // producer polled by this lane

    float c = 0.f;
    float h = 0.f;

    wait_chunk(cnt, 0);
    uint2 xraw = *(const uint2*)(xu + ((size_t)(g * 16 + r) << 12) + cb * 128 + hc * 4);

    for (int t = 0; t < 512; ++t) {
        f32x4 acc[8];
#pragma unroll
        for (int nt = 0; nt < 8; ++nt) acc[nt] = f32x4{0.f, 0.f, 0.f, 0.f};

        if (t) {
            // 1) poll this wave's 4 producers (lanes replicate x16; ballot all-set)
            for (;;) {
                u32 f = __hip_atomic_load(gflags + myp, __ATOMIC_RELAXED,
                                          __HIP_MEMORY_SCOPE_AGENT);
                if (__ballot(f >= (u32)t) == ~0ull) break;
                __builtin_amdgcn_s_sleep(1);
            }
            asm volatile("" ::: "memory");        // keep h loads below the poll

            // 2) stream h fragments: 4x16B uncached loads, full-line MALL reads
            const u16* hB = hhi + (((size_t)(t & 1) * 4 + g) * 16 + l15) * 1024
                          + wv * 128 + quad * 8;
            u32x4 hv[4];
#pragma unroll
            for (int j = 0; j < 4; ++j)
                hv[j] = load16_uc(hB + j * 32);
#pragma unroll
            for (int j = 0; j < 4; ++j) {
                wait_vm4(j, hv[j]);               // counted wait, ties block MFMA hoist
                union { u32x4 q; f16x8 v; } ah;
                ah.q = hv[j];
#pragma unroll
                for (int nt = 0; nt < 8; ++nt)
                    acc[nt] = __builtin_amdgcn_mfma_f32_16x16x32_f16(ah.v, vfrag[nt][j], acc[nt], 0, 0, 0);
            }
        }

        // 3) split-K partial handoff: C layout col=l15, row=quad*4+rg
#pragma unroll
        for (int nt = 0; nt < 8; ++nt)
#pragma unroll
            for (int rg = 0; rg < 4; ++rg)
                zs[wv][quad * 4 + rg][nt * 16 + l15] = acc[nt][rg];
        __syncthreads();

        float4 s = {0.f, 0.f, 0.f, 0.f};
#pragma unroll
        for (int w = 0; w < 8; ++w) {
            float4 v = *(const float4*)&zs[w][r][hc * 4];
            s.x += v.x; s.y += v.y; s.z += v.z; s.w += v.w;
        }
        float z0 = s.x + bf2f(xraw.x & 0xFFFFu);
        float z1 = s.y + bf2f(xraw.x >> 16);
        float z2 = s.z + bf2f(xraw.y & 0xFFFFu);
        float z3 = s.w + bf2f(xraw.y >> 16);

        float it_ = fast_sigmoid(z0);
        float ft_ = fast_sigmoid(z1);
        float gt_ = fast_tanh(z2);
        float ot_ = fast_tanh(z3);   // reference uses tanh for output gate
        c = ft_ * c + it_ * gt_;
        h = ot_ * fast_tanh(c);

        if (t == 511) break;     // final h never read back

        // 4) publish h (single fp16 write-through) + drain (stores only) + flag
        size_t sidx = (((size_t)((t + 1) & 1) * 4 + g) * 16 + r) * 1024 + cb * 32 + hc;
        __hip_atomic_store(hhi + sidx, f2h(h), __ATOMIC_RELAXED,
                           __HIP_MEMORY_SCOPE_AGENT);
        asm volatile("s_waitcnt vmcnt(0)" ::: "memory");
        __syncthreads();          // also protects zs reuse next iteration
        if (tid == 0)
            __hip_atomic_store(gflags + cb, (u32)(t + 1), __ATOMIC_RELAXED,
                               __HIP_MEMORY_SCOPE_AGENT);

        // 5) prefetch next xu AFTER the flag (chunk-gated every 128 steps;
        //    gate is after the flag store so it never extends the publish path)
        if (((t + 1) & 127) == 0) wait_chunk(cnt, (t + 1) >> 7);
        xraw = *(const uint2*)(xu + ((size_t)((t + 1) * 64 + g * 16 + r) << 12) + cb * 128 + hc * 4);
    }

    out[(size_t)(g * 16 + r) * 1024 + cb * 32 + hc] = h;
}

extern "C" void kernel_launch(void* const* d_in, const int* in_sizes, int n_in,
                              void* d_out, int out_size, void* d_ws, size_t ws_size,
                              hipStream_t stream) {
    char* ws = (char*)d_ws;
    const float* x = (const float*)d_in[0];
    const float *U[4], *V[4], *b[4];
    for (int g = 0; g < 4; ++g) {
        U[g] = (const float*)d_in[1 + 3 * g];
        V[g] = (const float*)d_in[2 + 3 * g];
        b[g] = (const float*)d_in[3 + 3 * g];
    }
    float* out = (float*)d_out;

    void* args[] = {(void*)&x,
                    (void*)&U[0], (void*)&V[0], (void*)&b[0],
                    (void*)&U[1], (void*)&V[1], (void*)&b[1],
                    (void*)&U[2], (void*)&V[2], (void*)&b[2],
                    (void*)&U[3], (void*)&V[3], (void*)&b[3],
                    (void*)&ws, (void*)&out};
    hipLaunchCooperativeKernel((const void*)lstm_fused_kernel, dim3(256), dim3(512),
                               args, 0, stream);
}

// Round 11
// 2327.310 us; speedup vs baseline: 1.1592x; 1.0067x over previous
//
#include <hip/hip_runtime.h>

using u16 = unsigned short;
using u32 = unsigned int;
using u64 = unsigned long long;
using bf16x8 = __attribute__((ext_vector_type(8))) short;
using f16x8  = __attribute__((ext_vector_type(8))) _Float16;
using f32x4  = __attribute__((ext_vector_type(4))) float;
using u32x4  = __attribute__((ext_vector_type(4))) unsigned int;

// ---------------- workspace layout (bytes) ----------------
static constexpr size_t XU_OFF = 0;
static constexpr size_t XU_BYTES = (size_t)512 * 64 * 4096 * 2;      // 256 MiB
static constexpr size_t XB_OFF = XU_OFF + XU_BYTES;
static constexpr size_t XB_BYTES = (size_t)64 * 512 * 1024 * 2;      // 64 MiB
static constexpr size_t UT_OFF = XB_OFF + XB_BYTES;
static constexpr size_t WT_BYTES = (size_t)4096 * 1024 * 2;          // 8 MiB
static constexpr size_t VT_OFF = UT_OFF + WT_BYTES;
static constexpr size_t BP_OFF = VT_OFF + WT_BYTES;
static constexpr size_t BP_BYTES = 4096 * 4;
// h plane: [2 parity][4 group][16 row][1024 col] u16 (fp16)
static constexpr size_t HT_PLANE = (size_t)2 * 4 * 16 * 1024 * 2;    // 256 KiB
static constexpr size_t HHI_OFF = BP_OFF + BP_BYTES;
static constexpr size_t FLAG_OFF = HHI_OFF + HT_PLANE;
static constexpr size_t FLAG_BYTES = 4096;   // flags[g*64+cb] (1KB) + chunk cnt[4] @ +2048

__device__ __forceinline__ float bf2f(u32 u) {
    return __uint_as_float(u << 16);
}
__device__ __forceinline__ u16 f2bf(float f) {
    u32 u = __float_as_uint(f);
    u32 r = (u + 0x7FFFu + ((u >> 16) & 1u)) >> 16;
    return (u16)r;
}
__device__ __forceinline__ u16 f2h(float f) {
    _Float16 x = (_Float16)f;                     // RTN
    union { _Float16 h; u16 u; } cv;
    cv.h = x;
    return cv.u;
}

// fast gates: v_exp + v_rcp (err ~1e-7, far below bf16 pipeline noise)
__device__ __forceinline__ float fast_sigmoid(float x) {
    return __builtin_amdgcn_rcpf(1.f + __expf(-x));
}
__device__ __forceinline__ float fast_tanh(float x) {
    return 1.f - 2.f * __builtin_amdgcn_rcpf(1.f + __expf(2.f * x));
}

// 16B cache-bypassing load (full-64B-line MALL requests)
__device__ __forceinline__ u32x4 load16_uc(const u16* p) {
    u32x4 v;
    asm volatile("global_load_dwordx4 %0, %1, off sc0 sc1"
                 : "=v"(v)
                 : "v"(p));
    return v;
}

// 16B write-through store, MALL-ALLOCATING (sc0 sc1, no nt). Required for
// cross-XCD produce/consume of xu inside ONE kernel. Ledger: nt bypasses MALL
// allocation (consumer reads become HBM misses, +450us, R7); plain cached
// stores thrash MALL with dirty writebacks (FETCH 1.38GB, R8).
__device__ __forceinline__ void store16_wt(u16* p, u32x4 v) {
    asm volatile("global_store_dwordx4 %0, %1, off sc0 sc1"
                 :: "v"(p), "v"(v) : "memory");
}

// counted wait for h load j (4 loads issued; xu prefetch may be outstanding
// and is OLDER, so vmcnt(3-j) drains it first -- oldest-first is safe).
__device__ __forceinline__ void wait_vm4(int j, u32x4& a) {
    switch (j) {
    case 0:  asm volatile("s_waitcnt vmcnt(3)" : "+v"(a)); break;
    case 1:  asm volatile("s_waitcnt vmcnt(2)" : "+v"(a)); break;
    case 2:  asm volatile("s_waitcnt vmcnt(1)" : "+v"(a)); break;
    default: asm volatile("s_waitcnt vmcnt(0)" : "+v"(a)); break;
    }
}

// async global->LDS, 16B per lane (wave-uniform LDS base + lane*16)
__device__ __forceinline__ void gld16(const u16* g, u16* l) {
    __builtin_amdgcn_global_load_lds((const __attribute__((address_space(1))) void*)g,
                                     (__attribute__((address_space(3))) void*)l,
                                     16, 0, 0);
}

// xu t-chunk readiness gate (2048 tiles per chunk)
__device__ __forceinline__ void wait_chunk(const u32* cnt, int c) {
    for (;;) {
        u32 v = __hip_atomic_load(cnt + c, __ATOMIC_RELAXED, __HIP_MEMORY_SCOPE_AGENT);
        if (v >= 2048u) break;
        __builtin_amdgcn_s_sleep(8);
    }
    asm volatile("" ::: "memory");   // keep xu loads below the gate
}

// ------------- x fp32 -> bf16 -------------
__global__ void cvt_x_kernel(const float4* __restrict__ x, uint2* __restrict__ xb) {
    int i = blockIdx.x * 256 + threadIdx.x;
#pragma unroll
    for (int k = 0; k < 8; ++k) {
        int idx = i + k * 1048576;
        float4 v = x[idx];
        uint2 o;
        o.x = (u32)f2bf(v.x) | ((u32)f2bf(v.y) << 16);
        o.y = (u32)f2bf(v.z) | ((u32)f2bf(v.w) << 16);
        xb[idx] = o;
    }
}

// ------------- repack: U fp32->bf16, V fp32->fp16; K-contiguous, gate-interleaved columns -------------
__global__ void repack_kernel(const float* U0, const float* U1, const float* U2, const float* U3,
                              const float* V0, const float* V1, const float* V2, const float* V3,
                              u16* UT, u16* VT) {
    __shared__ u16 tile[64][65];
    int bx  = blockIdx.x;
    int mat = bx >> 8;
    int rem = bx & 255;
    int tf = rem >> 4, th = rem & 15;
    int f0 = tf * 64, h0 = th * 64;
    const float* srcs[8] = {U0, U1, U2, U3, V0, V1, V2, V3};
    const float* s = srcs[mat];
    u16* d = (mat < 4) ? UT : VT;
    bool isU = (mat < 4);
    int g = mat & 3;
    int c = threadIdx.x & 63;
    int r = threadIdx.x >> 6;
#pragma unroll
    for (int i = 0; i < 16; ++i) {
        int fr = r + i * 4;
        float v = s[(size_t)(f0 + fr) * 1024 + h0 + c];
        tile[fr][c] = isU ? f2bf(v) : f2h(v);
    }
    __syncthreads();
#pragma unroll
    for (int i = 0; i < 16; ++i) {
        int hcl = r + i * 4;
        d[(size_t)((h0 + hcl) * 4 + g) * 1024 + f0 + c] = tile[c][hcl];
    }
}

// ------------- bias pack -------------
__global__ void bias_kernel(const float* b0, const float* b1, const float* b2, const float* b3,
                            float* bp) {
    int n = blockIdx.x * 256 + threadIdx.x;
    int g = n & 3, hc = n >> 2;
    const float* bs[4] = {b0, b1, b2, b3};
    bp[n] = bs[g][hc];
}

// ------------- one 128x128 xU GEMM tile, 8 waves (512 threads) -------------
// Chunk-ordered tile index tau: tc=tau>>11 (t-chunk), b=(tau&2047)>>5, nt=tau&31,
// mt=b*4+tc. LDS-staged (one gld16 per matrix per K-step), MFMA 4x2 per wave.
// Epilogue: acc -> LDS C-tile (bf16+bias) -> coalesced 256B-per-16-lane
// write-through stores -> vmcnt drain -> barrier -> chunk counter bump.
__device__ __forceinline__ void gemm_tile(int tau,
        const u16* __restrict__ xb, const u16* __restrict__ UT,
        const float* __restrict__ bp, u16* __restrict__ xu,
        u16* As, u16* Bs, u16* Cs, u32* cnt) {
    int tc = tau >> 11, rem = tau & 2047;
    int b = rem >> 5, nt = rem & 31, mt = b * 4 + tc;
    int tid = threadIdx.x;
    int lane = tid & 63, wv = tid >> 6;
    int wm = wv >> 2, wn = wv & 3;                // 2 x 4 wave grid
    int l15 = lane & 15, quad = lane >> 4;

    // staging: 512 threads x 16B = 8KB = one full [128][32] tile per inst
    int idr = tid >> 2, idk = (tid & 3) * 8;
    const u16* aS = xb + (size_t)(mt * 128 + idr) * 1024 + idk;
    const u16* bS = UT + (size_t)(nt * 128 + idr) * 1024 + idk;
    u16* aD = As + (size_t)tid * 8;
    u16* bD = Bs + (size_t)tid * 8;

    f32x4 acc[4][2];
#pragma unroll
    for (int i = 0; i < 4; ++i)
#pragma unroll
        for (int j = 0; j < 2; ++j) acc[i][j] = f32x4{0.f, 0.f, 0.f, 0.f};

    float biasv[2];
#pragma unroll
    for (int j = 0; j < 2; ++j) biasv[j] = bp[nt * 128 + wn * 32 + j * 16 + l15];

    for (int k0 = 0; k0 < 1024; k0 += 32) {
        gld16(aS + k0, aD);
        gld16(bS + k0, bD);
        __syncthreads();                          // compiler drains vmcnt first
        bf16x8 af[4], bfv[2];
#pragma unroll
        for (int i = 0; i < 4; ++i)
            af[i] = *(const bf16x8*)(As + (size_t)(wm * 64 + i * 16 + l15) * 32 + quad * 8);
#pragma unroll
        for (int j = 0; j < 2; ++j)
            bfv[j] = *(const bf16x8*)(Bs + (size_t)(wn * 32 + j * 16 + l15) * 32 + quad * 8);
#pragma unroll
        for (int i = 0; i < 4; ++i)
#pragma unroll
            for (int j = 0; j < 2; ++j)
                acc[i][j] = __builtin_amdgcn_mfma_f32_16x16x32_bf16(af[i], bfv[j], acc[i][j], 0, 0, 0);
        __syncthreads();                          // protect LDS before next stage
    }

    // acc -> LDS C-tile (row-pad 136 u16 kills the 64-aligned bank repeat)
#pragma unroll
    for (int i = 0; i < 4; ++i)
#pragma unroll
        for (int j = 0; j < 2; ++j)
#pragma unroll
            for (int rg = 0; rg < 4; ++rg)
                Cs[(size_t)(wm * 64 + i * 16 + quad * 4 + rg) * 136 + wn * 32 + j * 16 + l15] =
                    f2bf(acc[i][j][rg] + biasv[j]);
    __syncthreads();

    // coalesced write-through: 16 lanes cover one 256B row-segment
#pragma unroll
    for (int p = 0; p < 4; ++p) {
        int id = p * 512 + tid;
        int row = id >> 4, q = id & 15;
        u32x4 v = *(const u32x4*)(Cs + (size_t)row * 136 + q * 8);
        int gr = mt * 128 + row;
        int t_i = gr & 511, b_i = gr >> 9;
        store16_wt(xu + (((size_t)(t_i * 64 + b_i)) << 12) + nt * 128 + q * 8, v);
    }
    asm volatile("s_waitcnt vmcnt(0)" ::: "memory");
    __syncthreads();                              // all waves' stores MALL-acked
    if (tid == 0)
        __hip_atomic_fetch_add(cnt + tc, 1u, __ATOMIC_RELAXED, __HIP_MEMORY_SCOPE_AGENT);
}

// ------------- fused kernel: xU GEMM overlapped with the recurrent scan -------------
// 256 blocks x 512 threads, 1/CU (118KB LDS). PHASE A: all blocks build xu
// t-chunk 0. Then blocks 0..127 run the round-5 scan; blocks 128..255 build
// chunks 1..3 (stride-128 tile order) -- with PACING: R6 measured phase B's
// unthrottled 380us burst (~1TB/s of MALL traffic) inflating the latency-
// chained scan by ~290us (queueing). ~10us s_sleep between tiles spreads the
// same traffic over ~860us at ~1/2.7 intensity. Deadlines hold with margin:
// chunk1 done ~280us (scan needs it at ~380-410us even at 2.2-3.2us/step),
// chunk2 ~580 (need ~820), chunk3 ~860 (need ~1230).
// R10 lesson (hang): no liveness may depend on unverified topology reads --
// this design has none (role split is pure blockIdx).
__global__ void __launch_bounds__(512, 2) lstm_fused_kernel(
        const u16* __restrict__ xb, const u16* __restrict__ UT,
        const float* __restrict__ bp, u16* __restrict__ xu,
        const u16* __restrict__ VT, u16* hhi, u32* flags, u32* cnt,
        float* __restrict__ out) {
    __shared__ u16 As[128 * 32];                  // 8 KB
    __shared__ u16 Bs[128 * 32];                  // 8 KB
    __shared__ u16 Cs[128 * 136];                 // 34 KB
    __shared__ float zs[8][16][132];              // 67.6 KB

    int bx = blockIdx.x;

    // ---- PHASE A: chunk 0 on the full GPU ----
    for (int p = 0; p < 8; ++p)
        gemm_tile(bx * 8 + p, xb, UT, bp, xu, As, Bs, Cs, cnt);

    if (bx >= 128) {
        // ---- PHASE B: chunks 1..3 on blocks 128..255, paced ----
        int gid = bx - 128;
        for (int p = 0; p < 48; ++p) {
            gemm_tile(2048 + p * 128 + gid, xb, UT, bp, xu, As, Bs, Cs, cnt);
            if (p != 47) {
                // ~10us pause: 3 x s_sleep(127) = 3*8128 cy at 2.4GHz
                for (int sl = 0; sl < 3; ++sl) __builtin_amdgcn_s_sleep(127);
            }
        }
        return;
    }

    // ---- recurrent scan (round-5 proven structure) ----
    int g  = bx & 3;
    int cb = bx >> 2;                             // 0..31
    int tid = threadIdx.x;
    int lane = tid & 63, wv = tid >> 6;           // wv 0..7
    int l15 = lane & 15, quad = lane >> 4;
    int r  = tid >> 5;                            // batch row within group, 0..15
    int hc = tid & 31;                            // h-col within block, 0..31

    // V fragments in registers (fp16, 128 VGPRs/lane, fixed across steps)
    f16x8 vfrag[8][4];
    {
        const u16* vb = VT + ((size_t)(cb * 128 + l15) * 1024) + wv * 128 + quad * 8;
#pragma unroll
        for (int nt = 0; nt < 8; ++nt)
#pragma unroll
            for (int j = 0; j < 4; ++j)
                vfrag[nt][j] = *(const f16x8*)(vb + (size_t)nt * 16 * 1024 + j * 32);
    }

    u32* gflags = flags + g * 64;
    int myp = 4 * wv + (lane & 3);                // producer polled by this lane

    float c = 0.f;
    float h = 0.f;

    wait_chunk(cnt, 0);
    uint2 xraw = *(const uint2*)(xu + ((size_t)(g * 16 + r) << 12) + cb * 128 + hc * 4);

    for (int t = 0; t < 512; ++t) {
        f32x4 acc[8];
#pragma unroll
        for (int nt = 0; nt < 8; ++nt) acc[nt] = f32x4{0.f, 0.f, 0.f, 0.f};

        if (t) {
            // 1) poll this wave's 4 producers (lanes replicate x16; ballot all-set)
            for (;;) {
                u32 f = __hip_atomic_load(gflags + myp, __ATOMIC_RELAXED,
                                          __HIP_MEMORY_SCOPE_AGENT);
                if (__ballot(f >= (u32)t) == ~0ull) break;
                __builtin_amdgcn_s_sleep(1);
            }
            asm volatile("" ::: "memory");        // keep h loads below the poll

            // 2) stream h fragments: 4x16B uncached loads, full-line MALL reads
            const u16* hB = hhi + (((size_t)(t & 1) * 4 + g) * 16 + l15) * 1024
                          + wv * 128 + quad * 8;
            u32x4 hv[4];
#pragma unroll
            for (int j = 0; j < 4; ++j)
                hv[j] = load16_uc(hB + j * 32);
#pragma unroll
            for (int j = 0; j < 4; ++j) {
                wait_vm4(j, hv[j]);               // counted wait, ties block MFMA hoist
                union { u32x4 q; f16x8 v; } ah;
                ah.q = hv[j];
#pragma unroll
                for (int nt = 0; nt < 8; ++nt)
                    acc[nt] = __builtin_amdgcn_mfma_f32_16x16x32_f16(ah.v, vfrag[nt][j], acc[nt], 0, 0, 0);
            }
        }

        // 3) split-K partial handoff: C layout col=l15, row=quad*4+rg
#pragma unroll
        for (int nt = 0; nt < 8; ++nt)
#pragma unroll
            for (int rg = 0; rg < 4; ++rg)
                zs[wv][quad * 4 + rg][nt * 16 + l15] = acc[nt][rg];
        __syncthreads();

        float4 s = {0.f, 0.f, 0.f, 0.f};
#pragma unroll
        for (int w = 0; w < 8; ++w) {
            float4 v = *(const float4*)&zs[w][r][hc * 4];
            s.x += v.x; s.y += v.y; s.z += v.z; s.w += v.w;
        }
        float z0 = s.x + bf2f(xraw.x & 0xFFFFu);
        float z1 = s.y + bf2f(xraw.x >> 16);
        float z2 = s.z + bf2f(xraw.y & 0xFFFFu);
        float z3 = s.w + bf2f(xraw.y >> 16);

        float it_ = fast_sigmoid(z0);
        float ft_ = fast_sigmoid(z1);
        float gt_ = fast_tanh(z2);
        float ot_ = fast_tanh(z3);   // reference uses tanh for output gate
        c = ft_ * c + it_ * gt_;
        h = ot_ * fast_tanh(c);

        if (t == 511) break;     // final h never read back

        // 4) publish h (single fp16 write-through) + drain (stores only) + flag
        size_t sidx = (((size_t)((t + 1) & 1) * 4 + g) * 16 + r) * 1024 + cb * 32 + hc;
        __hip_atomic_store(hhi + sidx, f2h(h), __ATOMIC_RELAXED,
                           __HIP_MEMORY_SCOPE_AGENT);
        asm volatile("s_waitcnt vmcnt(0)" ::: "memory");
        __syncthreads();          // also protects zs reuse next iteration
        if (tid == 0)
            __hip_atomic_store(gflags + cb, (u32)(t + 1), __ATOMIC_RELAXED,
                               __HIP_MEMORY_SCOPE_AGENT);

        // 5) prefetch next xu AFTER the flag (chunk-gated every 128 steps;
        //    gate is after the flag store so it never extends the publish path)
        if (((t + 1) & 127) == 0) wait_chunk(cnt, (t + 1) >> 7);
        xraw = *(const uint2*)(xu + ((size_t)((t + 1) * 64 + g * 16 + r) << 12) + cb * 128 + hc * 4);
    }

    out[(size_t)(g * 16 + r) * 1024 + cb * 32 + hc] = h;
}

extern "C" void kernel_launch(void* const* d_in, const int* in_sizes, int n_in,
                              void* d_out, int out_size, void* d_ws, size_t ws_size,
                              hipStream_t stream) {
    char* ws = (char*)d_ws;
    const float* x = (const float*)d_in[0];
    const float *U[4], *V[4], *b[4];
    for (int g = 0; g < 4; ++g) {
        U[g] = (const float*)d_in[1 + 3 * g];
        V[g] = (const float*)d_in[2 + 3 * g];
        b[g] = (const float*)d_in[3 + 3 * g];
    }
    u16*   xu = (u16*)(ws + XU_OFF);
    u16*   xb = (u16*)(ws + XB_OFF);
    u16*   UT = (u16*)(ws + UT_OFF);
    u16*   VT = (u16*)(ws + VT_OFF);
    float* bp = (float*)(ws + BP_OFF);
    u16*   hhi = (u16*)(ws + HHI_OFF);
    u32*   flags = (u32*)(ws + FLAG_OFF);
    u32*   cnt = (u32*)(ws + FLAG_OFF + 2048);
    float* out = (float*)d_out;

    // flags + chunk counters must start at 0
    hipMemsetAsync(ws + FLAG_OFF, 0, FLAG_BYTES, stream);

    cvt_x_kernel<<<4096, 256, 0, stream>>>((const float4*)x, (uint2*)xb);
    repack_kernel<<<2048, 256, 0, stream>>>(U[0], U[1], U[2], U[3],
                                            V[0], V[1], V[2], V[3], UT, VT);
    bias_kernel<<<16, 256, 0, stream>>>(b[0], b[1], b[2], b[3], bp);

    void* args[] = {(void*)&xb, (void*)&UT, (void*)&bp, (void*)&xu,
                    (void*)&VT, (void*)&hhi, (void*)&flags, (void*)&cnt,
                    (void*)&out};
    hipLaunchCooperativeKernel((const void*)lstm_fused_kernel, dim3(256), dim3(512),
                               args, 0, stream);
}

// Round 12
// 2150.411 us; speedup vs baseline: 1.2545x; 1.0823x over previous
//
#include <hip/hip_runtime.h>

using u16 = unsigned short;
using u32 = unsigned int;
using u64 = unsigned long long;
using bf16x8 = __attribute__((ext_vector_type(8))) short;
using f16x8  = __attribute__((ext_vector_type(8))) _Float16;
using f32x4  = __attribute__((ext_vector_type(4))) float;
using u32x4  = __attribute__((ext_vector_type(4))) unsigned int;

// ---------------- workspace layout (bytes) ----------------
static constexpr size_t XU_OFF = 0;
static constexpr size_t XU_BYTES = (size_t)512 * 64 * 4096 * 2;      // 256 MiB
static constexpr size_t XB_OFF = XU_OFF + XU_BYTES;
static constexpr size_t XB_BYTES = (size_t)64 * 512 * 1024 * 2;      // 64 MiB
static constexpr size_t UT_OFF = XB_OFF + XB_BYTES;
static constexpr size_t WT_BYTES = (size_t)4096 * 1024 * 2;          // 8 MiB
static constexpr size_t VT_OFF = UT_OFF + WT_BYTES;
static constexpr size_t BP_OFF = VT_OFF + WT_BYTES;
static constexpr size_t BP_BYTES = 4096 * 4;
// h plane: [2 parity][4 group][16 row][1024 col] u16 (fp16)
static constexpr size_t HT_PLANE = (size_t)2 * 4 * 16 * 1024 * 2;    // 256 KiB
static constexpr size_t HHI_OFF = BP_OFF + BP_BYTES;
static constexpr size_t FLAG_OFF = HHI_OFF + HT_PLANE;
static constexpr size_t FLAG_BYTES = 4096;   // flags[g*64+cb] (1KB) + chunk cnt[4] @ +2048

__device__ __forceinline__ float bf2f(u32 u) {
    return __uint_as_float(u << 16);
}
__device__ __forceinline__ u16 f2bf(float f) {
    u32 u = __float_as_uint(f);
    u32 r = (u + 0x7FFFu + ((u >> 16) & 1u)) >> 16;
    return (u16)r;
}
__device__ __forceinline__ u16 f2h(float f) {
    _Float16 x = (_Float16)f;                     // RTN
    union { _Float16 h; u16 u; } cv;
    cv.h = x;
    return cv.u;
}

// fast gates: v_exp + v_rcp (err ~1e-7, far below bf16 pipeline noise)
__device__ __forceinline__ float fast_sigmoid(float x) {
    return __builtin_amdgcn_rcpf(1.f + __expf(-x));
}
__device__ __forceinline__ float fast_tanh(float x) {
    return 1.f - 2.f * __builtin_amdgcn_rcpf(1.f + __expf(2.f * x));
}

// 16B cache-bypassing load (full-64B-line MALL requests)
__device__ __forceinline__ u32x4 load16_uc(const u16* p) {
    u32x4 v;
    asm volatile("global_load_dwordx4 %0, %1, off sc0 sc1"
                 : "=v"(v)
                 : "v"(p));
    return v;
}

// 16B write-through store, MALL-ALLOCATING (sc0 sc1, no nt). Required for
// cross-XCD produce/consume of xu inside ONE kernel. Ledger: nt bypasses MALL
// allocation (consumer reads become HBM misses, +450us, R7); plain cached
// stores thrash MALL with dirty writebacks (FETCH 1.38GB, R8).
__device__ __forceinline__ void store16_wt(u16* p, u32x4 v) {
    asm volatile("global_store_dwordx4 %0, %1, off sc0 sc1"
                 :: "v"(p), "v"(v) : "memory");
}

// counted wait for h load j (4 loads issued; xu prefetch may be outstanding
// and is OLDER, so vmcnt(3-j) drains it first -- oldest-first is safe).
__device__ __forceinline__ void wait_vm4(int j, u32x4& a) {
    switch (j) {
    case 0:  asm volatile("s_waitcnt vmcnt(3)" : "+v"(a)); break;
    case 1:  asm volatile("s_waitcnt vmcnt(2)" : "+v"(a)); break;
    case 2:  asm volatile("s_waitcnt vmcnt(1)" : "+v"(a)); break;
    default: asm volatile("s_waitcnt vmcnt(0)" : "+v"(a)); break;
    }
}

// async global->LDS, 16B per lane (wave-uniform LDS base + lane*16)
__device__ __forceinline__ void gld16(const u16* g, u16* l) {
    __builtin_amdgcn_global_load_lds((const __attribute__((address_space(1))) void*)g,
                                     (__attribute__((address_space(3))) void*)l,
                                     16, 0, 0);
}

// xu t-chunk readiness gate (2048 tiles per chunk)
__device__ __forceinline__ void wait_chunk(const u32* cnt, int c) {
    for (;;) {
        u32 v = __hip_atomic_load(cnt + c, __ATOMIC_RELAXED, __HIP_MEMORY_SCOPE_AGENT);
        if (v >= 2048u) break;
        __builtin_amdgcn_s_sleep(8);
    }
    asm volatile("" ::: "memory");   // keep xu loads below the gate
}

// ------------- merged prep: cvt_x + U/V repack + bias pack + flag zero -------------
// One launch replaces 4 kernels + memset (R6 had ~195us of host-side gaps for
// ~50us of GPU work; R9's mistake was folding prep into the 256-block coop
// kernel where it ran slow -- here it keeps its original wide grids).
// bx <  4096          : cvt_x body   (4096 x 256, 8 float4 each)
// bx <  6144          : repack body  (2048 blocks, verbatim round-5)
// bx <  6160          : bias body    (16 blocks)
// bx == 6160          : zero flags + chunk counters (agent-scope stores)
__global__ void __launch_bounds__(256) prep_kernel(
        const float* __restrict__ x,
        const float* U0, const float* U1, const float* U2, const float* U3,
        const float* V0, const float* V1, const float* V2, const float* V3,
        const float* b0, const float* b1, const float* b2, const float* b3,
        u16* __restrict__ xb, u16* __restrict__ UT, u16* __restrict__ VT,
        float* __restrict__ bp, u32* __restrict__ flags) {
    __shared__ u16 tile[64][65];
    int bx = blockIdx.x;
    int tid = threadIdx.x;

    if (bx < 4096) {            // ---- x fp32 -> bf16 ----
        const float4* x4 = (const float4*)x;
        uint2* xb4 = (uint2*)xb;
        int i = bx * 256 + tid;
#pragma unroll
        for (int k = 0; k < 8; ++k) {
            int idx = i + k * 1048576;
            float4 v = x4[idx];
            uint2 o;
            o.x = (u32)f2bf(v.x) | ((u32)f2bf(v.y) << 16);
            o.y = (u32)f2bf(v.z) | ((u32)f2bf(v.w) << 16);
            xb4[idx] = o;
        }
    } else if (bx < 6144) {     // ---- U/V repack (U->bf16, V->fp16) ----
        int rbx = bx - 4096;
        int mat = rbx >> 8;
        int rem = rbx & 255;
        int tf = rem >> 4, th = rem & 15;
        int f0 = tf * 64, h0 = th * 64;
        const float* srcs[8] = {U0, U1, U2, U3, V0, V1, V2, V3};
        const float* s = srcs[mat];
        u16* d = (mat < 4) ? UT : VT;
        bool isU = (mat < 4);
        int g = mat & 3;
        int c = tid & 63;
        int r = tid >> 6;
#pragma unroll
        for (int i = 0; i < 16; ++i) {
            int fr = r + i * 4;
            float v = s[(size_t)(f0 + fr) * 1024 + h0 + c];
            tile[fr][c] = isU ? f2bf(v) : f2h(v);
        }
        __syncthreads();
#pragma unroll
        for (int i = 0; i < 16; ++i) {
            int hcl = r + i * 4;
            d[(size_t)((h0 + hcl) * 4 + g) * 1024 + f0 + c] = tile[c][hcl];
        }
    } else if (bx < 6160) {     // ---- bias pack ----
        int n = (bx - 6144) * 256 + tid;
        int g = n & 3, hc = n >> 2;
        const float* bs[4] = {b0, b1, b2, b3};
        bp[n] = bs[g][hc];
    } else {                    // ---- zero flags + chunk counters ----
#pragma unroll
        for (int k = 0; k < 4; ++k)
            __hip_atomic_store(flags + tid * 4 + k, 0u, __ATOMIC_RELAXED,
                               __HIP_MEMORY_SCOPE_AGENT);
    }
}

// ------------- one 128x128 xU GEMM tile, 8 waves (512 threads) -------------
// Chunk-ordered tile index tau: tc=tau>>11 (t-chunk), b=(tau&2047)>>5, nt=tau&31,
// mt=b*4+tc. LDS-staged (one gld16 per matrix per K-step), MFMA 4x2 per wave.
// Epilogue: acc -> LDS C-tile (bf16+bias) -> coalesced 256B-per-16-lane
// write-through stores -> vmcnt drain -> barrier -> chunk counter bump.
__device__ __forceinline__ void gemm_tile(int tau,
        const u16* __restrict__ xb, const u16* __restrict__ UT,
        const float* __restrict__ bp, u16* __restrict__ xu,
        u16* As, u16* Bs, u16* Cs, u32* cnt) {
    int tc = tau >> 11, rem = tau & 2047;
    int b = rem >> 5, nt = rem & 31, mt = b * 4 + tc;
    int tid = threadIdx.x;
    int lane = tid & 63, wv = tid >> 6;
    int wm = wv >> 2, wn = wv & 3;                // 2 x 4 wave grid
    int l15 = lane & 15, quad = lane >> 4;

    // staging: 512 threads x 16B = 8KB = one full [128][32] tile per inst
    int idr = tid >> 2, idk = (tid & 3) * 8;
    const u16* aS = xb + (size_t)(mt * 128 + idr) * 1024 + idk;
    const u16* bS = UT + (size_t)(nt * 128 + idr) * 1024 + idk;
    u16* aD = As + (size_t)tid * 8;
    u16* bD = Bs + (size_t)tid * 8;

    f32x4 acc[4][2];
#pragma unroll
    for (int i = 0; i < 4; ++i)
#pragma unroll
        for (int j = 0; j < 2; ++j) acc[i][j] = f32x4{0.f, 0.f, 0.f, 0.f};

    float biasv[2];
#pragma unroll
    for (int j = 0; j < 2; ++j) biasv[j] = bp[nt * 128 + wn * 32 + j * 16 + l15];

    for (int k0 = 0; k0 < 1024; k0 += 32) {
        gld16(aS + k0, aD);
        gld16(bS + k0, bD);
        __syncthreads();                          // compiler drains vmcnt first
        bf16x8 af[4], bfv[2];
#pragma unroll
        for (int i = 0; i < 4; ++i)
            af[i] = *(const bf16x8*)(As + (size_t)(wm * 64 + i * 16 + l15) * 32 + quad * 8);
#pragma unroll
        for (int j = 0; j < 2; ++j)
            bfv[j] = *(const bf16x8*)(Bs + (size_t)(wn * 32 + j * 16 + l15) * 32 + quad * 8);
#pragma unroll
        for (int i = 0; i < 4; ++i)
#pragma unroll
            for (int j = 0; j < 2; ++j)
                acc[i][j] = __builtin_amdgcn_mfma_f32_16x16x32_bf16(af[i], bfv[j], acc[i][j], 0, 0, 0);
        __syncthreads();                          // protect LDS before next stage
    }

    // acc -> LDS C-tile (row-pad 136 u16 kills the 64-aligned bank repeat)
#pragma unroll
    for (int i = 0; i < 4; ++i)
#pragma unroll
        for (int j = 0; j < 2; ++j)
#pragma unroll
            for (int rg = 0; rg < 4; ++rg)
                Cs[(size_t)(wm * 64 + i * 16 + quad * 4 + rg) * 136 + wn * 32 + j * 16 + l15] =
                    f2bf(acc[i][j][rg] + biasv[j]);
    __syncthreads();

    // coalesced write-through: 16 lanes cover one 256B row-segment
#pragma unroll
    for (int p = 0; p < 4; ++p) {
        int id = p * 512 + tid;
        int row = id >> 4, q = id & 15;
        u32x4 v = *(const u32x4*)(Cs + (size_t)row * 136 + q * 8);
        int gr = mt * 128 + row;
        int t_i = gr & 511, b_i = gr >> 9;
        store16_wt(xu + (((size_t)(t_i * 64 + b_i)) << 12) + nt * 128 + q * 8, v);
    }
    asm volatile("s_waitcnt vmcnt(0)" ::: "memory");
    __syncthreads();                              // all waves' stores MALL-acked
    if (tid == 0)
        __hip_atomic_fetch_add(cnt + tc, 1u, __ATOMIC_RELAXED, __HIP_MEMORY_SCOPE_AGENT);
}

// ------------- fused kernel: xU GEMM overlapped with the recurrent scan -------------
// R6-verbatim (best known: kernel 1997us). 256 blocks x 512 threads, 1/CU
// (118KB LDS). PHASE A: all blocks build xu t-chunk 0. Then blocks 0..127 run
// the round-5 scan; blocks 128..255 build chunks 1..3 UNPACED (R11 refuted
// pacing: interference is ~linear in overlap duration, not in instantaneous
// rate -- stretching the window with sleeps cost +126us). Chunk gating via
// per-chunk counters (target 2048).
__global__ void __launch_bounds__(512, 2) lstm_fused_kernel(
        const u16* __restrict__ xb, const u16* __restrict__ UT,
        const float* __restrict__ bp, u16* __restrict__ xu,
        const u16* __restrict__ VT, u16* hhi, u32* flags, u32* cnt,
        float* __restrict__ out) {
    __shared__ u16 As[128 * 32];                  // 8 KB
    __shared__ u16 Bs[128 * 32];                  // 8 KB
    __shared__ u16 Cs[128 * 136];                 // 34 KB
    __shared__ float zs[8][16][132];              // 67.6 KB

    int bx = blockIdx.x;

    // ---- PHASE A: chunk 0 on the full GPU ----
    for (int p = 0; p < 8; ++p)
        gemm_tile(bx * 8 + p, xb, UT, bp, xu, As, Bs, Cs, cnt);

    if (bx >= 128) {
        // ---- PHASE B: chunks 1..3 on blocks 128..255 ----
        int gid = bx - 128;
        for (int p = 0; p < 48; ++p)
            gemm_tile(2048 + p * 128 + gid, xb, UT, bp, xu, As, Bs, Cs, cnt);
        return;
    }

    // ---- recurrent scan (round-5 proven structure) ----
    int g  = bx & 3;
    int cb = bx >> 2;                             // 0..31
    int tid = threadIdx.x;
    int lane = tid & 63, wv = tid >> 6;           // wv 0..7
    int l15 = lane & 15, quad = lane >> 4;
    int r  = tid >> 5;                            // batch row within group, 0..15
    int hc = tid & 31;                            // h-col within block, 0..31

    // V fragments in registers (fp16, 128 VGPRs/lane, fixed across steps)
    f16x8 vfrag[8][4];
    {
        const u16* vb = VT + ((size_t)(cb * 128 + l15) * 1024) + wv * 128 + quad * 8;
#pragma unroll
        for (int nt = 0; nt < 8; ++nt)
#pragma unroll
            for (int j = 0; j < 4; ++j)
                vfrag[nt][j] = *(const f16x8*)(vb + (size_t)nt * 16 * 1024 + j * 32);
    }

    u32* gflags = flags + g * 64;
    int myp = 4 * wv + (lane & 3);                // producer polled by this lane

    float c = 0.f;
    float h = 0.f;

    wait_chunk(cnt, 0);
    uint2 xraw = *(const uint2*)(xu + ((size_t)(g * 16 + r) << 12) + cb * 128 + hc * 4);

    for (int t = 0; t < 512; ++t) {
        f32x4 acc[8];
#pragma unroll
        for (int nt = 0; nt < 8; ++nt) acc[nt] = f32x4{0.f, 0.f, 0.f, 0.f};

        if (t) {
            // 1) poll this wave's 4 producers (lanes replicate x16; ballot all-set)
            for (;;) {
                u32 f = __hip_atomic_load(gflags + myp, __ATOMIC_RELAXED,
                                          __HIP_MEMORY_SCOPE_AGENT);
                if (__ballot(f >= (u32)t) == ~0ull) break;
                __builtin_amdgcn_s_sleep(1);
            }
            asm volatile("" ::: "memory");        // keep h loads below the poll

            // 2) stream h fragments: 4x16B uncached loads, full-line MALL reads
            const u16* hB = hhi + (((size_t)(t & 1) * 4 + g) * 16 + l15) * 1024
                          + wv * 128 + quad * 8;
            u32x4 hv[4];
#pragma unroll
            for (int j = 0; j < 4; ++j)
                hv[j] = load16_uc(hB + j * 32);
#pragma unroll
            for (int j = 0; j < 4; ++j) {
                wait_vm4(j, hv[j]);               // counted wait, ties block MFMA hoist
                union { u32x4 q; f16x8 v; } ah;
                ah.q = hv[j];
#pragma unroll
                for (int nt = 0; nt < 8; ++nt)
                    acc[nt] = __builtin_amdgcn_mfma_f32_16x16x32_f16(ah.v, vfrag[nt][j], acc[nt], 0, 0, 0);
            }
        }

        // 3) split-K partial handoff: C layout col=l15, row=quad*4+rg
#pragma unroll
        for (int nt = 0; nt < 8; ++nt)
#pragma unroll
            for (int rg = 0; rg < 4; ++rg)
                zs[wv][quad * 4 + rg][nt * 16 + l15] = acc[nt][rg];
        __syncthreads();

        float4 s = {0.f, 0.f, 0.f, 0.f};
#pragma unroll
        for (int w = 0; w < 8; ++w) {
            float4 v = *(const float4*)&zs[w][r][hc * 4];
            s.x += v.x; s.y += v.y; s.z += v.z; s.w += v.w;
        }
        float z0 = s.x + bf2f(xraw.x & 0xFFFFu);
        float z1 = s.y + bf2f(xraw.x >> 16);
        float z2 = s.z + bf2f(xraw.y & 0xFFFFu);
        float z3 = s.w + bf2f(xraw.y >> 16);

        float it_ = fast_sigmoid(z0);
        float ft_ = fast_sigmoid(z1);
        float gt_ = fast_tanh(z2);
        float ot_ = fast_tanh(z3);   // reference uses tanh for output gate
        c = ft_ * c + it_ * gt_;
        h = ot_ * fast_tanh(c);

        if (t == 511) break;     // final h never read back

        // 4) publish h (single fp16 write-through) + drain (stores only) + flag
        size_t sidx = (((size_t)((t + 1) & 1) * 4 + g) * 16 + r) * 1024 + cb * 32 + hc;
        __hip_atomic_store(hhi + sidx, f2h(h), __ATOMIC_RELAXED,
                           __HIP_MEMORY_SCOPE_AGENT);
        asm volatile("s_waitcnt vmcnt(0)" ::: "memory");
        __syncthreads();          // also protects zs reuse next iteration
        if (tid == 0)
            __hip_atomic_store(gflags + cb, (u32)(t + 1), __ATOMIC_RELAXED,
                               __HIP_MEMORY_SCOPE_AGENT);

        // 5) prefetch next xu AFTER the flag (chunk-gated every 128 steps;
        //    gate is after the flag store so it never extends the publish path)
        if (((t + 1) & 127) == 0) wait_chunk(cnt, (t + 1) >> 7);
        xraw = *(const uint2*)(xu + ((size_t)((t + 1) * 64 + g * 16 + r) << 12) + cb * 128 + hc * 4);
    }

    out[(size_t)(g * 16 + r) * 1024 + cb * 32 + hc] = h;
}

extern "C" void kernel_launch(void* const* d_in, const int* in_sizes, int n_in,
                              void* d_out, int out_size, void* d_ws, size_t ws_size,
                              hipStream_t stream) {
    char* ws = (char*)d_ws;
    const float* x = (const float*)d_in[0];
    const float *U[4], *V[4], *b[4];
    for (int g = 0; g < 4; ++g) {
        U[g] = (const float*)d_in[1 + 3 * g];
        V[g] = (const float*)d_in[2 + 3 * g];
        b[g] = (const float*)d_in[3 + 3 * g];
    }
    u16*   xu = (u16*)(ws + XU_OFF);
    u16*   xb = (u16*)(ws + XB_OFF);
    u16*   UT = (u16*)(ws + UT_OFF);
    u16*   VT = (u16*)(ws + VT_OFF);
    float* bp = (float*)(ws + BP_OFF);
    u16*   hhi = (u16*)(ws + HHI_OFF);
    u32*   flags = (u32*)(ws + FLAG_OFF);
    u32*   cnt = (u32*)(ws + FLAG_OFF + 2048);
    float* out = (float*)d_out;

    // ONE prep launch: cvt + repack + bias + flag/cnt zero (replaces 4 kernels
    // + memset; R6 paid ~195us of host-side gaps for ~50us of GPU work)
    prep_kernel<<<6161, 256, 0, stream>>>(x,
                                          U[0], U[1], U[2], U[3],
                                          V[0], V[1], V[2], V[3],
                                          b[0], b[1], b[2], b[3],
                                          xb, UT, VT, bp, flags);

    void* args[] = {(void*)&xb, (void*)&UT, (void*)&bp, (void*)&xu,
                    (void*)&VT, (void*)&hhi, (void*)&flags, (void*)&cnt,
                    (void*)&out};
    hipLaunchCooperativeKernel((const void*)lstm_fused_kernel, dim3(256), dim3(512),
                               args, 0, stream);
}